// Round 5
// baseline (257.542 us; speedup 1.0000x reference)
//
#include <hip/hip_runtime.h>

typedef unsigned short u16;
typedef __attribute__((ext_vector_type(8))) short bfrag;   // 8 x bf16
typedef __attribute__((ext_vector_type(4))) float f32x4;

#define SROW 1032   // padded LDS row stride (bf16 elems): 2064 B
#define NBLK 64     // 1024 / 16
#define ACCW 20     // sh_acc row stride (16 + 4 pad)

__device__ __forceinline__ u16 f2bf(float x) {
    unsigned int v = __float_as_uint(x);
    return (u16)((v + 0x7FFFu + ((v >> 16) & 1u)) >> 16);   // RNE
}

// tanh(x) = 1 - 2/(e^{2x}+1): 5-op dependent chain, inf-safe.
__device__ __forceinline__ float fast_tanh(float x) {
    float e = __builtin_amdgcn_exp2f(x * 2.885390081777927f);
    return __builtin_fmaf(-2.0f, __builtin_amdgcn_rcpf(e + 1.0f), 1.0f);
}

// ---------------- prologue: bf16 conversions + 16x16 diag-block transpose ----------------
__global__ void ren_prologue(const float* __restrict__ Bs, const float* __restrict__ Bw,
                             const float* __restrict__ Ds, const float* __restrict__ Dw,
                             u16* __restrict__ bs16, u16* __restrict__ bw16,
                             u16* __restrict__ ds16, u16* __restrict__ dw16,
                             float* __restrict__ diagT)
{
    const int g = blockIdx.x * 256 + threadIdx.x;
    if (g < 262144) {
        const int idx = g * 4;
        const int i = idx >> 10, j = idx & 1023;
        const float4 v = *reinterpret_cast<const float4*>(Bs + idx);
        u16 o[4];
        o[0] = (j + 0 < i) ? f2bf(v.x) : (u16)0;
        o[1] = (j + 1 < i) ? f2bf(v.y) : (u16)0;
        o[2] = (j + 2 < i) ? f2bf(v.z) : (u16)0;
        o[3] = (j + 3 < i) ? f2bf(v.w) : (u16)0;
        *reinterpret_cast<uint2*>(bs16 + idx) = *reinterpret_cast<const uint2*>(o);
    } else if (g < 294912) {
        const int idx = (g - 262144) * 4;
        const float4 v = *reinterpret_cast<const float4*>(Bw + idx);
        u16 o[4] = { f2bf(v.x), f2bf(v.y), f2bf(v.z), f2bf(v.w) };
        *reinterpret_cast<uint2*>(bw16 + idx) = *reinterpret_cast<const uint2*>(o);
    } else if (g < 327680) {
        const int idx = (g - 294912) * 4;
        const float4 v = *reinterpret_cast<const float4*>(Ds + idx);
        u16 o[4] = { f2bf(v.x), f2bf(v.y), f2bf(v.z), f2bf(v.w) };
        *reinterpret_cast<uint2*>(ds16 + idx) = *reinterpret_cast<const uint2*>(o);
    } else if (g < 331776) {
        const int idx = (g - 327680) * 4;
        const float4 v = *reinterpret_cast<const float4*>(Dw + idx);
        u16 o[4] = { f2bf(v.x), f2bf(v.y), f2bf(v.z), f2bf(v.w) };
        *reinterpret_cast<uint2*>(dw16 + idx) = *reinterpret_cast<const uint2*>(o);
    } else if (g < 335872) {
        const int lin0 = (g - 331776) * 4;
        #pragma unroll
        for (int t = 0; t < 4; ++t) {
            const int l = lin0 + t;
            const int bb = l >> 8, rem = l & 255, i = rem >> 4, j = rem & 15;
            // diagT[b][i][j] = Bs[16b+j, 16b+i] for j>i (weight from unit i to unit j)
            diagT[l] = (j > i) ? Bs[(size_t)(bb * 16 + j) * 1024 + (bb * 16 + i)] : 0.0f;
        }
    }
}

// ---------------- main: pipelined triangular recurrence, BLK=16, 2-chain serial ----------------
// 256 wgs x 192 threads, 32 batch rows/wg. Waves 0,1: GEMM producers (m-tile=wave).
// Wave 2: serial consumer; chain A = rows 0-15 (lanes 0-15), chain B = rows 16-31 (lanes 16-31).
__global__ __launch_bounds__(192) void ren_main(
    const float* __restrict__ u,
    const u16* __restrict__ bs16, const u16* __restrict__ bw16,
    const u16* __restrict__ ds16, const u16* __restrict__ dw16,
    const float* __restrict__ diagT,
    float* __restrict__ out)
{
    __shared__ __align__(16) u16   sh_S[33 * SROW];    // rows 0-31 + dummy row 32
    __shared__ __align__(16) float sh_acc[32 * ACCW];  // pre-activation tile [32][16+pad]
    __shared__ __align__(16) float sh_dT[2][256];      // dbuf diag block f32 [16][16]

    const int tid  = threadIdx.x;
    const int wave = tid >> 6;
    const int lane = tid & 63;
    const int mt   = wave;                 // m-tile for GEMM waves
    const int lr   = lane & 15;
    const int lk8  = (lane >> 4) << 3;
    const int row0 = blockIdx.x << 5;      // 32 batch rows per wg

    // zero s history (future columns must read as 0 for the parity-chunk GEMM)
    for (int e = tid * 8; e < 33 * SROW; e += 192 * 8)
        *reinterpret_cast<uint4*>(sh_S + e) = (uint4){0u, 0u, 0u, 0u};

    bfrag fu[4];                           // u A-frags (GEMM waves only)
    f32x4 acc;                             // target-block accumulator

    if (wave < 2) {
        const float* up = u + (size_t)(row0 + mt * 16 + lr) * 128 + lk8;
        #pragma unroll
        for (int kk = 0; kk < 4; ++kk) {
            float4 a = *reinterpret_cast<const float4*>(up + kk * 32);
            float4 c = *reinterpret_cast<const float4*>(up + kk * 32 + 4);
            bfrag f;
            f[0] = (short)f2bf(a.x); f[1] = (short)f2bf(a.y);
            f[2] = (short)f2bf(a.z); f[3] = (short)f2bf(a.w);
            f[4] = (short)f2bf(c.x); f[5] = (short)f2bf(c.y);
            f[6] = (short)f2bf(c.z); f[7] = (short)f2bf(c.w);
            fu[kk] = f;
        }
        if (tid < 128) {   // stage dT block 0 (256 f32 by 128 threads)
            float2 d0 = reinterpret_cast<const float2*>(diagT)[tid];
            reinterpret_cast<float2*>(&sh_dT[0][0])[tid] = d0;
        }
        // block 0 pre-activations = Bu only
        acc = (f32x4){0.f, 0.f, 0.f, 0.f};
        const u16* p0 = bw16 + (size_t)lr * 128 + lk8;
        #pragma unroll
        for (int kk = 0; kk < 4; ++kk)
            acc = __builtin_amdgcn_mfma_f32_16x16x32_bf16(fu[kk], *reinterpret_cast<const bfrag*>(p0 + kk * 32), acc, 0, 0, 0);
        const int m = (mt << 4) + ((lane >> 4) << 2);
        #pragma unroll
        for (int rr = 0; rr < 4; ++rr)
            sh_acc[(m + rr) * ACCW + lr] = acc[rr];
    }
    __syncthreads();

    for (int b = 0; b < NBLK; ++b) {
        if (wave == 2) {
            // ---------- serial: 16 steps, two independent chains ----------
            const float* accr = sh_acc + (lane & 31) * ACCW;
            float pA[16], pB[16];
            #pragma unroll
            for (int q = 0; q < 4; ++q) {
                float4 v = reinterpret_cast<const float4*>(accr)[q];
                pA[4*q+0] = v.x; pA[4*q+1] = v.y; pA[4*q+2] = v.z; pA[4*q+3] = v.w;
                pB[4*q+0] = v.x; pB[4*q+1] = v.y; pB[4*q+2] = v.z; pB[4*q+3] = v.w;
            }
            const float4* dT4 = reinterpret_cast<const float4*>(&sh_dT[b & 1][0]);
            float4 wreg[3][4];
            #pragma unroll
            for (int q = 0; q < 4; ++q) wreg[0][q] = dT4[q];
            #pragma unroll
            for (int q = 0; q < 4; ++q) wreg[1][q] = dT4[4 + q];
            const bool isA = (lane < 16);
            u16* srow = sh_S + min(lane, 32) * SROW + (b << 4);
            #pragma unroll
            for (int i = 0; i < 16; ++i) {
                if (i + 2 < 16) {
                    #pragma unroll
                    for (int q = (i + 3) >> 2; q < 4; ++q)
                        wreg[(i + 2) % 3][q] = dT4[((i + 2) << 2) + q];
                }
                float sA = fast_tanh(pA[i]);
                float sB = fast_tanh(pB[i]);
                float ss = isA ? sA : sB;
                srow[i] = (u16)((__float_as_uint(ss) + 0x8000u) >> 16);
                #pragma unroll
                for (int q = (i + 1) >> 2; q < 4; ++q) {
                    float4 w = wreg[i % 3][q];   // zero-padded for j<=i
                    pA[4*q+0] = __builtin_fmaf(w.x, sA, pA[4*q+0]);
                    pA[4*q+1] = __builtin_fmaf(w.y, sA, pA[4*q+1]);
                    pA[4*q+2] = __builtin_fmaf(w.z, sA, pA[4*q+2]);
                    pA[4*q+3] = __builtin_fmaf(w.w, sA, pA[4*q+3]);
                    pB[4*q+0] = __builtin_fmaf(w.x, sB, pB[4*q+0]);
                    pB[4*q+1] = __builtin_fmaf(w.y, sB, pB[4*q+1]);
                    pB[4*q+2] = __builtin_fmaf(w.z, sB, pB[4*q+2]);
                    pB[4*q+3] = __builtin_fmaf(w.w, sB, pB[4*q+3]);
                }
            }
        }

        bfrag bfin;                        // finish-chunk B-frag, preloaded pre-barrier
        const int nb = b + 1;
        const int tf = b >> 1;             // finish chunk (covers cols 32tf..32tf+31)
        if (wave < 2 && b < NBLK - 1) {
            // ---------- GEMM producers: target block nb ----------
            float2 dstage;
            if (tid < 128) dstage = reinterpret_cast<const float2*>(diagT + (nb << 8))[tid];
            bfin = *reinterpret_cast<const bfrag*>(bs16 + (size_t)((nb << 4) + lr) * 1024 + (tf << 5) + lk8);

            acc = (f32x4){0.f, 0.f, 0.f, 0.f};
            const u16* p0 = bw16 + (size_t)((nb << 4) + lr) * 128 + lk8;
            #pragma unroll
            for (int kk = 0; kk < 4; ++kk)
                acc = __builtin_amdgcn_mfma_f32_16x16x32_bf16(fu[kk], *reinterpret_cast<const bfrag*>(p0 + kk * 32), acc, 0, 0, 0);

            const u16* bsp = bs16 + (size_t)((nb << 4) + lr) * 1024 + lk8;
            const u16* ssp = sh_S + ((mt << 4) + lr) * SROW + lk8;
            const int npart = b >> 1;      // chunks t < b/2 touch only finalized blocks
            #pragma unroll 8
            for (int t = 0; t < npart; ++t) {
                bfrag af = *reinterpret_cast<const bfrag*>(ssp + (t << 5));
                acc = __builtin_amdgcn_mfma_f32_16x16x32_bf16(af, *reinterpret_cast<const bfrag*>(bsp + (t << 5)), acc, 0, 0, 0);
            }
            if (tid < 128) reinterpret_cast<float2*>(&sh_dT[nb & 1][0])[tid] = dstage;
        }
        __syncthreads();   // s_b visible; partials done

        if (wave < 2 && b < NBLK - 1) {
            // ---------- finish: one MFMA on chunk tf (fresh block b; future cols are 0) ----------
            const u16* ssp = sh_S + ((mt << 4) + lr) * SROW + lk8;
            bfrag af = *reinterpret_cast<const bfrag*>(ssp + (tf << 5));
            acc = __builtin_amdgcn_mfma_f32_16x16x32_bf16(af, bfin, acc, 0, 0, 0);
            const int m = (mt << 4) + ((lane >> 4) << 2);
            #pragma unroll
            for (int rr = 0; rr < 4; ++rr)
                sh_acc[(m + rr) * ACCW + lr] = acc[rr];
        }
        __syncthreads();   // sh_acc ready for serial(b+1)
    }

    if (wave >= 2) return;

    // ---------------- epilogue: y = s @ Ds^T + u @ D^T ----------------
    f32x4 ey[8];
    #pragma unroll
    for (int t = 0; t < 8; ++t) ey[t] = (f32x4){0.f, 0.f, 0.f, 0.f};

    const u16* ssp = sh_S + ((mt << 4) + lr) * SROW + lk8;
    #pragma unroll 2
    for (int kc = 0; kc < 32; ++kc) {
        bfrag af = *reinterpret_cast<const bfrag*>(ssp + (kc << 5));
        #pragma unroll
        for (int t = 0; t < 8; ++t) {
            bfrag bf = *reinterpret_cast<const bfrag*>(ds16 + (size_t)(t * 16 + lr) * 1024 + (kc << 5) + lk8);
            ey[t] = __builtin_amdgcn_mfma_f32_16x16x32_bf16(af, bf, ey[t], 0, 0, 0);
        }
    }
    #pragma unroll
    for (int kk = 0; kk < 4; ++kk) {
        #pragma unroll
        for (int t = 0; t < 8; ++t) {
            bfrag bf = *reinterpret_cast<const bfrag*>(dw16 + (t * 16 + lr) * 128 + (kk << 5) + lk8);
            ey[t] = __builtin_amdgcn_mfma_f32_16x16x32_bf16(fu[kk], bf, ey[t], 0, 0, 0);
        }
    }
    {
        const int mbase = row0 + (mt << 4) + ((lane >> 4) << 2);
        #pragma unroll
        for (int t = 0; t < 8; ++t) {
            #pragma unroll
            for (int rr = 0; rr < 4; ++rr)
                out[(size_t)(mbase + rr) * 128 + t * 16 + lr] = ey[t][rr];
        }
    }
}

extern "C" void kernel_launch(void* const* d_in, const int* in_sizes, int n_in,
                              void* d_out, int out_size, void* d_ws, size_t ws_size,
                              hipStream_t stream)
{
    const float* u  = (const float*)d_in[0];   // [8192,128]
    const float* Bw = (const float*)d_in[1];   // [1024,128]
    const float* Bs = (const float*)d_in[2];   // [1024,1024]
    const float* Ds = (const float*)d_in[3];   // [128,1024]
    const float* Dw = (const float*)d_in[4];   // [128,128]
    float* out = (float*)d_out;

    u16* bs16 = (u16*)d_ws;                    // 1024*1024 bf16
    u16* bw16 = bs16 + 1024 * 1024;            // 1024*128
    u16* ds16 = bw16 + 1024 * 128;             // 128*1024
    u16* dw16 = ds16 + 128 * 1024;             // 128*128
    float* diagT = (float*)(dw16 + 128 * 128); // 64 blocks x 16x16 f32, transposed

    ren_prologue<<<1312, 256, 0, stream>>>(Bs, Bw, Ds, Dw, bs16, bw16, ds16, dw16, diagT);
    ren_main<<<256, 192, 0, stream>>>(u, bs16, bw16, ds16, dw16, diagT, out);
}

// Round 6
// 235.144 us; speedup vs baseline: 1.0953x; 1.0953x over previous
//
#include <hip/hip_runtime.h>

typedef unsigned short u16;
typedef __attribute__((ext_vector_type(8))) short bfrag;   // 8 x bf16
typedef __attribute__((ext_vector_type(4))) float f32x4;

#define SROW 1032   // padded LDS row stride (bf16 elems): 2064 B
#define ACCW 36     // sh_acc row stride in f32 (16B-aligned rows, 2-way-max banks)

__device__ __forceinline__ u16 f2bf(float x) {
    unsigned int v = __float_as_uint(x);
    return (u16)((v + 0x7FFFu + ((v >> 16) & 1u)) >> 16);   // RNE
}

// tanh(x) = 1 - 2/(e^{2x}+1): 5-op dependent chain, inf-safe.
__device__ __forceinline__ float fast_tanh(float x) {
    float e = __builtin_amdgcn_exp2f(x * 2.885390081777927f);
    return __builtin_fmaf(-2.0f, __builtin_amdgcn_rcpf(e + 1.0f), 1.0f);
}

// ---------------- prologue: bf16 conversions + 32x32 diag-block transpose ----------------
__global__ void ren_prologue(const float* __restrict__ Bs, const float* __restrict__ Bw,
                             const float* __restrict__ Ds, const float* __restrict__ Dw,
                             u16* __restrict__ bs16, u16* __restrict__ bw16,
                             u16* __restrict__ ds16, u16* __restrict__ dw16,
                             float* __restrict__ diagT)
{
    const int g = blockIdx.x * 256 + threadIdx.x;
    if (g < 262144) {
        const int idx = g * 4;
        const int i = idx >> 10, j = idx & 1023;
        const float4 v = *reinterpret_cast<const float4*>(Bs + idx);
        u16 o[4];
        o[0] = (j + 0 < i) ? f2bf(v.x) : (u16)0;
        o[1] = (j + 1 < i) ? f2bf(v.y) : (u16)0;
        o[2] = (j + 2 < i) ? f2bf(v.z) : (u16)0;
        o[3] = (j + 3 < i) ? f2bf(v.w) : (u16)0;
        *reinterpret_cast<uint2*>(bs16 + idx) = *reinterpret_cast<const uint2*>(o);
    } else if (g < 294912) {
        const int idx = (g - 262144) * 4;
        const float4 v = *reinterpret_cast<const float4*>(Bw + idx);
        u16 o[4] = { f2bf(v.x), f2bf(v.y), f2bf(v.z), f2bf(v.w) };
        *reinterpret_cast<uint2*>(bw16 + idx) = *reinterpret_cast<const uint2*>(o);
    } else if (g < 327680) {
        const int idx = (g - 294912) * 4;
        const float4 v = *reinterpret_cast<const float4*>(Ds + idx);
        u16 o[4] = { f2bf(v.x), f2bf(v.y), f2bf(v.z), f2bf(v.w) };
        *reinterpret_cast<uint2*>(ds16 + idx) = *reinterpret_cast<const uint2*>(o);
    } else if (g < 331776) {
        const int idx = (g - 327680) * 4;
        const float4 v = *reinterpret_cast<const float4*>(Dw + idx);
        u16 o[4] = { f2bf(v.x), f2bf(v.y), f2bf(v.z), f2bf(v.w) };
        *reinterpret_cast<uint2*>(dw16 + idx) = *reinterpret_cast<const uint2*>(o);
    } else if (g < 339968) {
        const int lin0 = (g - 331776) * 4;
        #pragma unroll
        for (int t = 0; t < 4; ++t) {
            const int l = lin0 + t;
            const int bb = l >> 10, rem = l & 1023, i = rem >> 5, j = rem & 31;
            // diagT[b][i][j] = Bs[32b+j, 32b+i] for j>i (weight from unit i to unit j)
            diagT[l] = (j > i) ? Bs[(size_t)(bb * 32 + j) * 1024 + (bb * 32 + i)] : 0.0f;
        }
    }
}

// ---------------- main: barrier-free per-wave triangular recurrence ----------------
// 512 wgs x 64 threads (ONE wave each), 16 batch rows per wg. No __syncthreads in
// the main loop: GEMM, transpose, and serial phase all run in the same wave,
// ordered by the hardware lgkm/vm counters (compiler-inserted waits).
__global__ __launch_bounds__(64) void ren_main(
    const float* __restrict__ u,
    const u16* __restrict__ bs16, const u16* __restrict__ bw16,
    const u16* __restrict__ ds16, const u16* __restrict__ dw16,
    const float* __restrict__ diagT,
    float* __restrict__ out)
{
    __shared__ __align__(16) u16   sh_S[16 * SROW];     // s history bf16 [16][1024+pad]
    __shared__ __align__(16) float sh_acc[16 * ACCW];   // transpose tile [16][36]
    __shared__ __align__(16) float sh_dT[2][1024];      // dbuf diag block f32 [32][32]

    const int lane = threadIdx.x;
    const int lr   = lane & 15;
    const int lk8  = (lane >> 4) << 3;
    const int row0 = blockIdx.x << 4;      // 16 batch rows per wg

    // u A-fragments for the 16 rows (k = 0..127)
    bfrag fu[4];
    {
        const float* up = u + (size_t)(row0 + lr) * 128 + lk8;
        #pragma unroll
        for (int kk = 0; kk < 4; ++kk) {
            float4 a = *reinterpret_cast<const float4*>(up + kk * 32);
            float4 c = *reinterpret_cast<const float4*>(up + kk * 32 + 4);
            bfrag f;
            f[0] = (short)f2bf(a.x); f[1] = (short)f2bf(a.y);
            f[2] = (short)f2bf(a.z); f[3] = (short)f2bf(a.w);
            f[4] = (short)f2bf(c.x); f[5] = (short)f2bf(c.y);
            f[6] = (short)f2bf(c.z); f[7] = (short)f2bf(c.w);
            fu[kk] = f;
        }
    }

    float4 st[4];      // in-flight dT staging registers
    f32x4 acc0, acc1;
    float part[32];

    // ---- bootstrap: stage dT(0); acc(0) = Bu(0); transpose -> part ----
    {
        const float4* g = reinterpret_cast<const float4*>(diagT);
        #pragma unroll
        for (int t = 0; t < 4; ++t) st[t] = g[4 * lane + t];
        float4* dd = reinterpret_cast<float4*>(&sh_dT[0][0]);
        #pragma unroll
        for (int t = 0; t < 4; ++t) dd[4 * lane + t] = st[t];

        acc0 = (f32x4){0.f,0.f,0.f,0.f}; acc1 = (f32x4){0.f,0.f,0.f,0.f};
        const u16* p0 = bw16 + (size_t)lr * 128 + lk8;
        const u16* p1 = bw16 + (size_t)(16 + lr) * 128 + lk8;
        #pragma unroll
        for (int kk = 0; kk < 4; ++kk) {
            acc0 = __builtin_amdgcn_mfma_f32_16x16x32_bf16(fu[kk], *reinterpret_cast<const bfrag*>(p0 + kk * 32), acc0, 0, 0, 0);
            acc1 = __builtin_amdgcn_mfma_f32_16x16x32_bf16(fu[kk], *reinterpret_cast<const bfrag*>(p1 + kk * 32), acc1, 0, 0, 0);
        }
        const int m = (lane >> 4) << 2;
        #pragma unroll
        for (int rr = 0; rr < 4; ++rr) {
            sh_acc[(m + rr) * ACCW + lr]      = acc0[rr];
            sh_acc[(m + rr) * ACCW + 16 + lr] = acc1[rr];
        }
        if (lane < 16) {
            const float4* ar = reinterpret_cast<const float4*>(sh_acc + lane * ACCW);
            #pragma unroll
            for (int q = 0; q < 8; ++q) {
                float4 v = ar[q];
                part[4*q+0] = v.x; part[4*q+1] = v.y; part[4*q+2] = v.z; part[4*q+3] = v.w;
            }
        }
    }

    for (int b = 0; b < 32; ++b) {
        const int nb = b + 1;
        // (A) issue next dT block's global loads; they fly during the serial phase
        if (nb < 32) {
            const float4* g = reinterpret_cast<const float4*>(diagT + (nb << 10));
            #pragma unroll
            for (int t = 0; t < 4; ++t) st[t] = g[4 * lane + t];
        }

        // (B) serial: 32 steps, lanes 0-15 (lane = batch row)
        if (lane < 16) {
            const float4* dT4 = reinterpret_cast<const float4*>(&sh_dT[b & 1][0]);
            float4 wreg[3][8];
            #pragma unroll
            for (int q = 0; q < 8; ++q) wreg[0][q] = dT4[q];
            #pragma unroll
            for (int q = 0; q < 8; ++q) wreg[1][q] = dT4[8 + q];
            u16* srow = sh_S + lane * SROW + (b << 5);
            u16 sv[8];
            #pragma unroll
            for (int i = 0; i < 32; ++i) {
                if (i + 2 < 32) {
                    #pragma unroll
                    for (int q = (i + 3) >> 2; q < 8; ++q)
                        wreg[(i + 2) % 3][q] = dT4[((i + 2) << 3) + q];
                }
                float s = fast_tanh(part[i]);
                sv[i & 7] = (u16)((__float_as_uint(s) + 0x8000u) >> 16);
                if ((i & 7) == 7) {
                    uint4 pk;
                    pk.x = (unsigned)sv[0] | ((unsigned)sv[1] << 16);
                    pk.y = (unsigned)sv[2] | ((unsigned)sv[3] << 16);
                    pk.z = (unsigned)sv[4] | ((unsigned)sv[5] << 16);
                    pk.w = (unsigned)sv[6] | ((unsigned)sv[7] << 16);
                    *reinterpret_cast<uint4*>(srow + ((i >> 3) << 3)) = pk;
                }
                #pragma unroll
                for (int q = (i + 1) >> 2; q < 8; ++q) {
                    float4 w = wreg[i % 3][q];   // zero-padded for j<=i
                    part[4*q+0] = __builtin_fmaf(w.x, s, part[4*q+0]);
                    part[4*q+1] = __builtin_fmaf(w.y, s, part[4*q+1]);
                    part[4*q+2] = __builtin_fmaf(w.z, s, part[4*q+2]);
                    part[4*q+3] = __builtin_fmaf(w.w, s, part[4*q+3]);
                }
            }
        }

        // (C) GEMM for block b+1 (kc = 0..b, incl. fresh s_b) + transpose -> part
        if (nb < 32) {
            float4* dd = reinterpret_cast<float4*>(&sh_dT[nb & 1][0]);
            #pragma unroll
            for (int t = 0; t < 4; ++t) dd[4 * lane + t] = st[t];

            acc0 = (f32x4){0.f,0.f,0.f,0.f}; acc1 = (f32x4){0.f,0.f,0.f,0.f};
            const u16* q0 = bw16 + (size_t)((nb << 5) + lr) * 128 + lk8;
            const u16* q1 = bw16 + (size_t)((nb << 5) + 16 + lr) * 128 + lk8;
            #pragma unroll
            for (int kk = 0; kk < 4; ++kk) {
                acc0 = __builtin_amdgcn_mfma_f32_16x16x32_bf16(fu[kk], *reinterpret_cast<const bfrag*>(q0 + kk * 32), acc0, 0, 0, 0);
                acc1 = __builtin_amdgcn_mfma_f32_16x16x32_bf16(fu[kk], *reinterpret_cast<const bfrag*>(q1 + kk * 32), acc1, 0, 0, 0);
            }
            const u16* bsp0 = bs16 + (size_t)((nb << 5) + lr) * 1024 + lk8;
            const u16* bsp1 = bs16 + (size_t)((nb << 5) + 16 + lr) * 1024 + lk8;
            const u16* ssp  = sh_S + lr * SROW + lk8;
            #pragma unroll 8
            for (int kc = 0; kc <= b; ++kc) {
                bfrag af = *reinterpret_cast<const bfrag*>(ssp + (kc << 5));
                acc0 = __builtin_amdgcn_mfma_f32_16x16x32_bf16(af, *reinterpret_cast<const bfrag*>(bsp0 + (kc << 5)), acc0, 0, 0, 0);
                acc1 = __builtin_amdgcn_mfma_f32_16x16x32_bf16(af, *reinterpret_cast<const bfrag*>(bsp1 + (kc << 5)), acc1, 0, 0, 0);
            }
            const int m = (lane >> 4) << 2;
            #pragma unroll
            for (int rr = 0; rr < 4; ++rr) {
                sh_acc[(m + rr) * ACCW + lr]      = acc0[rr];
                sh_acc[(m + rr) * ACCW + 16 + lr] = acc1[rr];
            }
            if (lane < 16) {
                const float4* ar = reinterpret_cast<const float4*>(sh_acc + lane * ACCW);
                #pragma unroll
                for (int q = 0; q < 8; ++q) {
                    float4 v = ar[q];
                    part[4*q+0] = v.x; part[4*q+1] = v.y; part[4*q+2] = v.z; part[4*q+3] = v.w;
                }
            }
        }
    }

    // ---------------- epilogue: y = s @ Ds^T + u @ D^T  (16 x 128 per wg) ----------------
    f32x4 ey[8];
    #pragma unroll
    for (int t = 0; t < 8; ++t) ey[t] = (f32x4){0.f,0.f,0.f,0.f};

    const u16* ssp = sh_S + lr * SROW + lk8;
    #pragma unroll 2
    for (int kc = 0; kc < 32; ++kc) {
        bfrag af = *reinterpret_cast<const bfrag*>(ssp + (kc << 5));
        #pragma unroll
        for (int t = 0; t < 8; ++t) {
            bfrag bf = *reinterpret_cast<const bfrag*>(ds16 + (size_t)(t * 16 + lr) * 1024 + (kc << 5) + lk8);
            ey[t] = __builtin_amdgcn_mfma_f32_16x16x32_bf16(af, bf, ey[t], 0, 0, 0);
        }
    }
    #pragma unroll
    for (int kk = 0; kk < 4; ++kk) {
        #pragma unroll
        for (int t = 0; t < 8; ++t) {
            bfrag bf = *reinterpret_cast<const bfrag*>(dw16 + (t * 16 + lr) * 128 + (kk << 5) + lk8);
            ey[t] = __builtin_amdgcn_mfma_f32_16x16x32_bf16(fu[kk], bf, ey[t], 0, 0, 0);
        }
    }
    {
        const int mbase = row0 + ((lane >> 4) << 2);
        #pragma unroll
        for (int t = 0; t < 8; ++t) {
            #pragma unroll
            for (int rr = 0; rr < 4; ++rr)
                out[(size_t)(mbase + rr) * 128 + t * 16 + lr] = ey[t][rr];
        }
    }
}

extern "C" void kernel_launch(void* const* d_in, const int* in_sizes, int n_in,
                              void* d_out, int out_size, void* d_ws, size_t ws_size,
                              hipStream_t stream)
{
    const float* u  = (const float*)d_in[0];   // [8192,128]
    const float* Bw = (const float*)d_in[1];   // [1024,128]
    const float* Bs = (const float*)d_in[2];   // [1024,1024]
    const float* Ds = (const float*)d_in[3];   // [128,1024]
    const float* Dw = (const float*)d_in[4];   // [128,128]
    float* out = (float*)d_out;

    u16* bs16 = (u16*)d_ws;                    // 1024*1024 bf16
    u16* bw16 = bs16 + 1024 * 1024;            // 1024*128
    u16* ds16 = bw16 + 1024 * 128;             // 128*1024
    u16* dw16 = ds16 + 128 * 1024;             // 128*128
    float* diagT = (float*)(dw16 + 128 * 128); // 32 blocks x 32x32 f32, transposed

    ren_prologue<<<1328, 256, 0, stream>>>(Bs, Bw, Ds, Dw, bs16, bw16, ds16, dw16, diagT);
    ren_main<<<512, 64, 0, stream>>>(u, bs16, bw16, ds16, dw16, diagT, out);
}